// Round 2
// baseline (523.599 us; speedup 1.0000x reference)
//
#include <hip/hip_runtime.h>
#include <math.h>

// ----------------------------------------------------------------------------
// MultiHeadAttentionQuantum: 8-qubit RX/CNOT-ring circuit projections + MHA.
//
// Round-2 restructure: the round-1 kernels were DS-pipe-bound (shuffle-heavy
// wave-per-sample sim ~165us, LDS-staged attn ~123us vs 43us HBM floor).
// This version is DS-free in the hot paths:
//
// qsim: 16 samples/wave, 4 lanes/sample (quad), 64 amps/lane.
//   Data index d in [0,256): d = (quadlane<<6) | loc. quadlane bit0 = data
//   bit6, bit1 = data bit7, loc = data bits 0..5.  Wire w <-> data bit 7-w.
//   All cross-lane gate masks (0x80,0x40,0xC0,0x60,0xC1) have lane-xor in
//   {1,2,3} = DPP quad_perm -> VALU pipe, zero DS ops. Intra-lane gates are
//   register permutations. Verified circuit algebra from round 1 (passed):
//     L1 RX masks e_w; L2 RX masks {C0,60,30,18,0C,06,03,C1};
//     readout parity masks {D5,BF,5F,AF,57,AB,55,AA}.
//   Readout: per-lane 6-stage local WHT (VALU) + 2-stage quad WHT (DPP).
//
// attn: one wave per 32 query rows; K/V held in VGPRs (lane owns 16
//   contiguous j), softmax reductions via DPP (quad_perm, row_half_mirror,
//   row_mirror) + shfl_xor 16/32 only; attn rows stored as dwordx4.
//
// Round-3: NON-TEMPORAL stores for the 268 MB attn matrix stream (write-once,
//   never GPU-re-read) so it does not evict reused K/V slices + qp rows from
//   L2. Round-4 fix: __builtin_nontemporal_store needs a NATIVE vector type
//   (ext_vector_type(4)), not HIP's float4 class.
// ----------------------------------------------------------------------------

#define NSAMP 32768  // B*S = 32*1024

typedef float floatx4 __attribute__((ext_vector_type(4)));

// DPP ctrl codes (gfx9/CDNA): quad_perm xor1/2/3, quad bcast j, row mirrors.
#define QX1 0xB1  // [1,0,3,2]
#define QX2 0x4E  // [2,3,0,1]
#define QX3 0x1B  // [3,2,1,0]
#define QB0 0x00
#define QB1 0x55
#define QB2 0xAA
#define QB3 0xFF
#define ROW_MIRROR 0x140       // lane ^ 15 within 16
#define ROW_HALF_MIRROR 0x141  // lane ^ 7 within 8

template <int CTRL>
__device__ __forceinline__ float dppf(float x) {
  int xi = __float_as_int(x);
  return __int_as_float(
      __builtin_amdgcn_update_dpp(xi, xi, CTRL, 0xF, 0xF, false));
}

// Intra-lane RX along local mask ML (pairwise in-place update).
template <int ML>
__device__ __forceinline__ void gate_l(float c, float s, float* ar,
                                       float* ai) {
  constexpr int HB = ML >= 32 ? 32 : ML >= 16 ? 16 : ML >= 8 ? 8
                     : ML >= 4 ? 4 : ML >= 2 ? 2 : 1;
#pragma unroll
  for (int l = 0; l < 64; ++l) {
    if (!(l & HB)) {
      const int p = l ^ ML;
      float a0r = ar[l], a0i = ai[l], a1r = ar[p], a1i = ai[p];
      ar[l] = fmaf(c, a0r, s * a1i);
      ai[l] = fmaf(c, a0i, -s * a1r);
      ar[p] = fmaf(c, a1r, s * a0i);
      ai[p] = fmaf(c, a1i, -s * a0r);
    }
  }
}

// Cross-quad RX: lane-xor via DPP quad_perm CTRL, plus local mask ML.
template <int CTRL, int ML>
__device__ __forceinline__ void gate_q(float c, float s, float* ar,
                                       float* ai) {
  if constexpr (ML == 0) {
#pragma unroll
    for (int l = 0; l < 64; ++l) {
      float pr = dppf<CTRL>(ar[l]);
      float pi = dppf<CTRL>(ai[l]);
      ar[l] = fmaf(c, ar[l], s * pi);
      ai[l] = fmaf(c, ai[l], -s * pr);
    }
  } else {
    constexpr int HB = ML >= 32 ? 32 : ML >= 16 ? 16 : ML >= 8 ? 8
                       : ML >= 4 ? 4 : ML >= 2 ? 2 : 1;
#pragma unroll
    for (int l = 0; l < 64; ++l) {
      if (!(l & HB)) {
        const int p = l ^ ML;
        float prl = dppf<CTRL>(ar[p]);  // partner of amp l
        float pil = dppf<CTRL>(ai[p]);
        float prp = dppf<CTRL>(ar[l]);  // partner of amp p
        float pip = dppf<CTRL>(ai[l]);
        ar[l] = fmaf(c, ar[l], s * pil);
        ai[l] = fmaf(c, ai[l], -s * prl);
        ar[p] = fmaf(c, ar[p], s * pip);
        ai[p] = fmaf(c, ai[p], -s * prp);
      }
    }
  }
}

// 2-stage signed quad WHT: returns, in quad-lane u, sum_q (-1)^<u,q> W_q.
__device__ __forceinline__ float quad_wht(float v, int qq) {
  float u = dppf<QX1>(v);
  v = (qq & 1) ? (u - v) : (v + u);
  u = dppf<QX2>(v);
  v = (qq & 2) ? (u - v) : (v + u);
  return v;
}

// in:  sample angle rows [samp][8]; wc/ws: per-proj cos/sin of 16 weight
// angles (LDS); out: [samp][8] expvals. Wave handles samples
// [sampBase, sampBase+16).
__device__ __forceinline__ void qsim_wave(const float* __restrict__ in,
                                          float* __restrict__ outp,
                                          int sampBase,
                                          const float* __restrict__ wc,
                                          const float* __restrict__ wsn) {
  const int lane = threadIdx.x & 63;
  const int qq = lane & 3;
  const int g = lane >> 2;
  const int samp = sampBase + g;

  // Input trig: lane qq computes wires 2qq, 2qq+1; quad-broadcast all 8.
  const float2 xx = *(const float2*)(in + (size_t)samp * 8 + 2 * qq);
  float h0 = 0.5f * xx.x, h1 = 0.5f * xx.y;
  float c0 = cosf(h0), s0 = sinf(h0);
  float c1 = cosf(h1), s1 = sinf(h1);
  float cw[8], sw[8];
  cw[0] = dppf<QB0>(c0); cw[1] = dppf<QB0>(c1);
  sw[0] = dppf<QB0>(s0); sw[1] = dppf<QB0>(s1);
  cw[2] = dppf<QB1>(c0); cw[3] = dppf<QB1>(c1);
  sw[2] = dppf<QB1>(s0); sw[3] = dppf<QB1>(s1);
  cw[4] = dppf<QB2>(c0); cw[5] = dppf<QB2>(c1);
  sw[4] = dppf<QB2>(s0); sw[5] = dppf<QB2>(s1);
  cw[6] = dppf<QB3>(c0); cw[7] = dppf<QB3>(c1);
  sw[6] = dppf<QB3>(s0); sw[7] = dppf<QB3>(s1);

  // Product-state magnitudes, built in-place in ar by tensor doubling.
  // loc bit k = data bit k = wire 7-k. quad bit0 = wire1, bit1 = wire0.
  float ar[64], ai[64];
  ar[0] = ((qq & 1) ? sw[1] : cw[1]) * ((qq & 2) ? sw[0] : cw[0]);
#pragma unroll
  for (int k = 0; k < 6; ++k) {
    const float cc = cw[7 - k], ss = sw[7 - k];
#pragma unroll
    for (int t = (1 << k) - 1; t >= 0; --t) {
      ar[t + (1 << k)] = ar[t] * ss;
      ar[t] = ar[t] * cc;
    }
  }
  // Phase (-i)^popcount(d): local part compile-time, quad part lane-uniform.
  {
    const int pq = __builtin_popcount(qq);
#pragma unroll
    for (int l = 63; l >= 0; --l) {
      const int pl = __builtin_popcount(l) & 3;
      const float mm = ar[l];
      if (pl == 0) { ar[l] = mm;   ai[l] = 0.0f; }
      else if (pl == 1) { ar[l] = 0.0f; ai[l] = -mm; }
      else if (pl == 2) { ar[l] = -mm;  ai[l] = 0.0f; }
      else { ar[l] = 0.0f; ai[l] = mm; }
    }
    // lane-uniform rotation by (-i)^pq: pq=1: (r,i)->(i,-r); pq=2: negate.
    if (pq == 1) {
#pragma unroll
      for (int l = 0; l < 64; ++l) {
        const float t = ar[l];
        ar[l] = ai[l];
        ai[l] = -t;
      }
    } else if (pq == 2) {
#pragma unroll
      for (int l = 0; l < 64; ++l) {
        ar[l] = -ar[l];
        ai[l] = -ai[l];
      }
    }
  }

  // Layer 1 RX (weight idx 0..7 = wires 0..7), masks e_{7-w}.
  gate_q<QX2, 0>(wc[0], wsn[0], ar, ai);      // 0x80
  gate_q<QX1, 0>(wc[1], wsn[1], ar, ai);      // 0x40
  gate_l<0x20>(wc[2], wsn[2], ar, ai);
  gate_l<0x10>(wc[3], wsn[3], ar, ai);
  gate_l<0x08>(wc[4], wsn[4], ar, ai);
  gate_l<0x04>(wc[5], wsn[5], ar, ai);
  gate_l<0x02>(wc[6], wsn[6], ar, ai);
  gate_l<0x01>(wc[7], wsn[7], ar, ai);
  // Layer 2 RX (idx 8..15), masks B1*e_w (verified round 1).
  gate_q<QX3, 0>(wc[8], wsn[8], ar, ai);      // 0xC0
  gate_q<QX1, 0x20>(wc[9], wsn[9], ar, ai);   // 0x60
  gate_l<0x30>(wc[10], wsn[10], ar, ai);
  gate_l<0x18>(wc[11], wsn[11], ar, ai);
  gate_l<0x0C>(wc[12], wsn[12], ar, ai);
  gate_l<0x06>(wc[13], wsn[13], ar, ai);
  gate_l<0x03>(wc[14], wsn[14], ar, ai);
  gate_q<QX3, 0x01>(wc[15], wsn[15], ar, ai); // 0xC1

  // Probabilities + full 6-stage local WHT: p[u] = sum_l (-1)^<u,l> |amp_l|^2.
  float p[64];
#pragma unroll
  for (int l = 0; l < 64; ++l) p[l] = ar[l] * ar[l] + ai[l] * ai[l];
#pragma unroll
  for (int k = 0; k < 6; ++k) {
#pragma unroll
    for (int l = 0; l < 64; ++l) {
      if (!(l & (1 << k))) {
        const int q2 = l | (1 << k);
        const float a = p[l], b = p[q2];
        p[l] = a + b;
        p[q2] = a - b;
      }
    }
  }
  // Readout masks r_i -> (quad part rq = r>>6, local part rl = r&0x3F):
  // i: 0:(3,0x15) 1:(2,0x3F) 2:(1,0x1F) 3:(2,0x2F) 4:(1,0x17) 5:(2,0x2B)
  //    6:(1,0x15) 7:(2,0x2A)
  const float o15 = quad_wht(p[0x15], qq);  // serves i0 (qq=3) and i6 (qq=1)
  const float o3F = quad_wht(p[0x3F], qq);
  const float o1F = quad_wht(p[0x1F], qq);
  const float o2F = quad_wht(p[0x2F], qq);
  const float o17 = quad_wht(p[0x17], qq);
  const float o2B = quad_wht(p[0x2B], qq);
  const float o2A = quad_wht(p[0x2A], qq);

  float* orow = outp + (size_t)samp * 8;
  if (qq == 3) orow[0] = o15;
  if (qq == 2) {
    orow[1] = o3F;
    orow[3] = o2F;
    orow[5] = o2B;
    orow[7] = o2A;
  }
  if (qq == 1) {
    orow[2] = o1F;
    orow[4] = o17;
    orow[6] = o15;
  }
}

// Per-block weight trig into LDS (threads 0..31), then qsim per wave.
__device__ __forceinline__ void weight_trig(const float* __restrict__ w,
                                            float* __restrict__ tc,
                                            float* __restrict__ tsn) {
  if (threadIdx.x < 32) {
    const int a = threadIdx.x & 15;
    const float half = 0.5f * w[a];
    if (threadIdx.x < 16)
      tc[a] = cosf(half);
    else
      tsn[a] = sinf(half);
  }
  __syncthreads();
}

__global__ __launch_bounds__(256, 2) void mhaq_qproj3_kernel(
    const float* __restrict__ q, const float* __restrict__ k,
    const float* __restrict__ v, const float* __restrict__ wq,
    const float* __restrict__ wk, const float* __restrict__ wv,
    float* __restrict__ qp, float* __restrict__ kp, float* __restrict__ vp) {
  __shared__ float tc[16], tsn[16];
  const int wg = blockIdx.x * 4 + (threadIdx.x >> 6);  // 0..6143
  const int proj = wg >> 11;  // 2048 waves per projection; block-uniform
  const float* wsel = proj == 0 ? wq : proj == 1 ? wk : wv;
  weight_trig(wsel, tc, tsn);
  const float* in = proj == 0 ? q : proj == 1 ? k : v;
  float* op = proj == 0 ? qp : proj == 1 ? kp : vp;
  qsim_wave(in, op, (wg & 2047) * 16, tc, tsn);
}

__global__ __launch_bounds__(256, 2) void mhaq_qproj1_kernel(
    const float* __restrict__ ctx, const float* __restrict__ wd,
    float* __restrict__ outp) {
  __shared__ float tc[16], tsn[16];
  weight_trig(wd, tc, tsn);
  const int wg = blockIdx.x * 4 + (threadIdx.x >> 6);  // 0..2047
  qsim_wave(ctx, outp, wg * 16, tc, tsn);
}

// Full-wave reductions: quad DPP + row mirrors + 2 shfl stages (only DS use).
__device__ __forceinline__ float wred_sum(float v) {
  v += dppf<QX1>(v);
  v += dppf<QX2>(v);
  v += dppf<ROW_HALF_MIRROR>(v);  // xor7 == xor4 after quad-uniform
  v += dppf<ROW_MIRROR>(v);       // xor15 == xor8 after 8-uniform
  v += __shfl_xor(v, 16, 64);
  v += __shfl_xor(v, 32, 64);
  return v;
}
__device__ __forceinline__ float wred_max(float v) {
  v = fmaxf(v, dppf<QX1>(v));
  v = fmaxf(v, dppf<QX2>(v));
  v = fmaxf(v, dppf<ROW_HALF_MIRROR>(v));
  v = fmaxf(v, dppf<ROW_MIRROR>(v));
  v = fmaxf(v, __shfl_xor(v, 16, 64));
  v = fmaxf(v, __shfl_xor(v, 32, 64));
  return v;
}

// Attention: one wave per (b,h, 32-row chunk); K/V head slice in VGPRs
// (lane owns j = lane*16..lane*16+15). HBM-write-bound on the attn matrix.
__global__ __launch_bounds__(256, 2) void mhaq_attn_kernel(
    const float* __restrict__ qp, const float* __restrict__ kp,
    const float* __restrict__ vp, float* __restrict__ ctx,
    float* __restrict__ attn) {
  const int wg = blockIdx.x * 4 + (threadIdx.x >> 6);  // 0..2047
  const int bh = wg >> 5;
  const int chunk = wg & 31;
  const int b = bh >> 1, h = bh & 1;
  const int lane = threadIdx.x & 63;

  float4 kreg[16], vreg[16];
  const float* kbase = kp + (size_t)b * 1024 * 8 + h * 4;
  const float* vbase = vp + (size_t)b * 1024 * 8 + h * 4;
#pragma unroll
  for (int t = 0; t < 16; ++t) {
    const size_t j = (size_t)lane * 16 + t;
    kreg[t] = *(const float4*)(kbase + j * 8);
    vreg[t] = *(const float4*)(vbase + j * 8);
  }

  for (int r = 0; r < 32; ++r) {
    const int i = chunk * 32 + r;
    const float4 qv = *(const float4*)(qp + ((size_t)b * 1024 + i) * 8 + h * 4);
    float e[16];
    float mx = -1e30f;
#pragma unroll
    for (int t = 0; t < 16; ++t) {
      float s = qv.x * kreg[t].x + qv.y * kreg[t].y + qv.z * kreg[t].z +
                qv.w * kreg[t].w;
      s *= 0.5f;  // 1/sqrt(D), D=4
      e[t] = s;
      mx = fmaxf(mx, s);
    }
    mx = wred_max(mx);
    float sum = 0.0f;
#pragma unroll
    for (int t = 0; t < 16; ++t) {
      e[t] = __expf(e[t] - mx);
      sum += e[t];
    }
    sum = wred_sum(sum);
    const float rinv = 1.0f / sum;

    float a0 = 0.f, a1 = 0.f, a2 = 0.f, a3 = 0.f;
    float* arow = attn + ((size_t)(bh * 1024 + i)) * 1024 + lane * 16;
#pragma unroll
    for (int u = 0; u < 4; ++u) {
      float p0 = e[4 * u] * rinv, p1 = e[4 * u + 1] * rinv,
            p2 = e[4 * u + 2] * rinv, p3 = e[4 * u + 3] * rinv;
      // Non-temporal: attn stream is write-once, never re-read on GPU;
      // keep it out of L2 so K/V slices + qp rows stay resident.
      floatx4 pv = {p0, p1, p2, p3};
      __builtin_nontemporal_store(pv, (floatx4*)(arow + 4 * u));
      a0 = fmaf(p0, vreg[4 * u].x, a0);
      a1 = fmaf(p0, vreg[4 * u].y, a1);
      a2 = fmaf(p0, vreg[4 * u].z, a2);
      a3 = fmaf(p0, vreg[4 * u].w, a3);
      a0 = fmaf(p1, vreg[4 * u + 1].x, a0);
      a1 = fmaf(p1, vreg[4 * u + 1].y, a1);
      a2 = fmaf(p1, vreg[4 * u + 1].z, a2);
      a3 = fmaf(p1, vreg[4 * u + 1].w, a3);
      a0 = fmaf(p2, vreg[4 * u + 2].x, a0);
      a1 = fmaf(p2, vreg[4 * u + 2].y, a1);
      a2 = fmaf(p2, vreg[4 * u + 2].z, a2);
      a3 = fmaf(p2, vreg[4 * u + 2].w, a3);
      a0 = fmaf(p3, vreg[4 * u + 3].x, a0);
      a1 = fmaf(p3, vreg[4 * u + 3].y, a1);
      a2 = fmaf(p3, vreg[4 * u + 3].z, a2);
      a3 = fmaf(p3, vreg[4 * u + 3].w, a3);
    }
    a0 = wred_sum(a0);
    a1 = wred_sum(a1);
    a2 = wred_sum(a2);
    a3 = wred_sum(a3);
    if (lane == 0)
      *(float4*)(ctx + ((size_t)b * 1024 + i) * 8 + h * 4) =
          make_float4(a0, a1, a2, a3);
  }
}

extern "C" void kernel_launch(void* const* d_in, const int* in_sizes, int n_in,
                              void* d_out, int out_size, void* d_ws,
                              size_t ws_size, hipStream_t stream) {
  (void)in_sizes; (void)n_in; (void)out_size; (void)ws_size;
  const float* q = (const float*)d_in[0];
  const float* k = (const float*)d_in[1];
  const float* v = (const float*)d_in[2];
  const float* wq = (const float*)d_in[3];
  const float* wk = (const float*)d_in[4];
  const float* wv = (const float*)d_in[5];
  const float* wd = (const float*)d_in[6];
  float* outp = (float*)d_out;  // [0, 262144): out; then attn (B,H,S,S)
  float* attn = outp + 262144;

  float* wsf = (float*)d_ws;
  float* qp = wsf;
  float* kp = qp + (size_t)NSAMP * 8;
  float* vp = kp + (size_t)NSAMP * 8;
  float* ctx = vp + (size_t)NSAMP * 8;  // concat layout [b,s,h*4+d]

  hipLaunchKernelGGL(mhaq_qproj3_kernel, dim3(1536), dim3(256), 0, stream, q,
                     k, v, wq, wk, wv, qp, kp, vp);
  hipLaunchKernelGGL(mhaq_attn_kernel, dim3(512), dim3(256), 0, stream, qp, kp,
                     vp, ctx, attn);
  hipLaunchKernelGGL(mhaq_qproj1_kernel, dim3(512), dim3(256), 0, stream, ctx,
                     wd, outp);
}

// Round 3
// 385.487 us; speedup vs baseline: 1.3583x; 1.3583x over previous
//
#include <hip/hip_runtime.h>
#include <math.h>

// ----------------------------------------------------------------------------
// MultiHeadAttentionQuantum: 8-qubit RX/CNOT-ring circuit projections + MHA.
//
// qsim: 16 samples/wave, 4 lanes/sample (quad), 64 amps/lane. DS-free:
//   cross-lane gates via DPP quad_perm; intra-lane gates are register
//   permutations; readout via 6-stage local WHT + 2-stage quad WHT.
//   Circuit algebra verified (passed): L1 RX masks e_w; L2 RX masks
//   {C0,60,30,18,0C,06,03,C1}; readout parity masks {D5,BF,5F,AF,57,AB,55,AA}.
//
// attn (round-5 rework): rocprof showed 217us, write BW 1.24 TB/s = 25% of
//   achievable -- the attn-matrix store was 64B-strided 16B/lane (nt store
//   bypassed L2 write-combining -> sparse HBM transactions). Fix:
//   (a) lane owns j = t*256 + lane*4 + c  => each wave store instruction is
//       one dense, aligned 1 KB block (plain stores, no nt);
//   (b) 8 query rows per wave (grid 2048 blocks) for 4x more outstanding
//       stores / better write-latency hiding. Reductions and PV are
//       ownership-agnostic, so softmax math is unchanged.
// ----------------------------------------------------------------------------

#define NSAMP 32768  // B*S = 32*1024

// DPP ctrl codes (gfx9/CDNA): quad_perm xor1/2/3, quad bcast j, row mirrors.
#define QX1 0xB1  // [1,0,3,2]
#define QX2 0x4E  // [2,3,0,1]
#define QX3 0x1B  // [3,2,1,0]
#define QB0 0x00
#define QB1 0x55
#define QB2 0xAA
#define QB3 0xFF
#define ROW_MIRROR 0x140       // lane ^ 15 within 16
#define ROW_HALF_MIRROR 0x141  // lane ^ 7 within 8

template <int CTRL>
__device__ __forceinline__ float dppf(float x) {
  int xi = __float_as_int(x);
  return __int_as_float(
      __builtin_amdgcn_update_dpp(xi, xi, CTRL, 0xF, 0xF, false));
}

// Intra-lane RX along local mask ML (pairwise in-place update).
template <int ML>
__device__ __forceinline__ void gate_l(float c, float s, float* ar,
                                       float* ai) {
  constexpr int HB = ML >= 32 ? 32 : ML >= 16 ? 16 : ML >= 8 ? 8
                     : ML >= 4 ? 4 : ML >= 2 ? 2 : 1;
#pragma unroll
  for (int l = 0; l < 64; ++l) {
    if (!(l & HB)) {
      const int p = l ^ ML;
      float a0r = ar[l], a0i = ai[l], a1r = ar[p], a1i = ai[p];
      ar[l] = fmaf(c, a0r, s * a1i);
      ai[l] = fmaf(c, a0i, -s * a1r);
      ar[p] = fmaf(c, a1r, s * a0i);
      ai[p] = fmaf(c, a1i, -s * a0r);
    }
  }
}

// Cross-quad RX: lane-xor via DPP quad_perm CTRL, plus local mask ML.
template <int CTRL, int ML>
__device__ __forceinline__ void gate_q(float c, float s, float* ar,
                                       float* ai) {
  if constexpr (ML == 0) {
#pragma unroll
    for (int l = 0; l < 64; ++l) {
      float pr = dppf<CTRL>(ar[l]);
      float pi = dppf<CTRL>(ai[l]);
      ar[l] = fmaf(c, ar[l], s * pi);
      ai[l] = fmaf(c, ai[l], -s * pr);
    }
  } else {
    constexpr int HB = ML >= 32 ? 32 : ML >= 16 ? 16 : ML >= 8 ? 8
                       : ML >= 4 ? 4 : ML >= 2 ? 2 : 1;
#pragma unroll
    for (int l = 0; l < 64; ++l) {
      if (!(l & HB)) {
        const int p = l ^ ML;
        float prl = dppf<CTRL>(ar[p]);  // partner of amp l
        float pil = dppf<CTRL>(ai[p]);
        float prp = dppf<CTRL>(ar[l]);  // partner of amp p
        float pip = dppf<CTRL>(ai[l]);
        ar[l] = fmaf(c, ar[l], s * pil);
        ai[l] = fmaf(c, ai[l], -s * prl);
        ar[p] = fmaf(c, ar[p], s * pip);
        ai[p] = fmaf(c, ai[p], -s * prp);
      }
    }
  }
}

// 2-stage signed quad WHT: returns, in quad-lane u, sum_q (-1)^<u,q> W_q.
__device__ __forceinline__ float quad_wht(float v, int qq) {
  float u = dppf<QX1>(v);
  v = (qq & 1) ? (u - v) : (v + u);
  u = dppf<QX2>(v);
  v = (qq & 2) ? (u - v) : (v + u);
  return v;
}

// in:  sample angle rows [samp][8]; wc/ws: per-proj cos/sin of 16 weight
// angles (LDS); out: [samp][8] expvals. Wave handles samples
// [sampBase, sampBase+16).
__device__ __forceinline__ void qsim_wave(const float* __restrict__ in,
                                          float* __restrict__ outp,
                                          int sampBase,
                                          const float* __restrict__ wc,
                                          const float* __restrict__ wsn) {
  const int lane = threadIdx.x & 63;
  const int qq = lane & 3;
  const int g = lane >> 2;
  const int samp = sampBase + g;

  // Input trig: lane qq computes wires 2qq, 2qq+1; quad-broadcast all 8.
  const float2 xx = *(const float2*)(in + (size_t)samp * 8 + 2 * qq);
  float h0 = 0.5f * xx.x, h1 = 0.5f * xx.y;
  float c0 = cosf(h0), s0 = sinf(h0);
  float c1 = cosf(h1), s1 = sinf(h1);
  float cw[8], sw[8];
  cw[0] = dppf<QB0>(c0); cw[1] = dppf<QB0>(c1);
  sw[0] = dppf<QB0>(s0); sw[1] = dppf<QB0>(s1);
  cw[2] = dppf<QB1>(c0); cw[3] = dppf<QB1>(c1);
  sw[2] = dppf<QB1>(s0); sw[3] = dppf<QB1>(s1);
  cw[4] = dppf<QB2>(c0); cw[5] = dppf<QB2>(c1);
  sw[4] = dppf<QB2>(s0); sw[5] = dppf<QB2>(s1);
  cw[6] = dppf<QB3>(c0); cw[7] = dppf<QB3>(c1);
  sw[6] = dppf<QB3>(s0); sw[7] = dppf<QB3>(s1);

  // Product-state magnitudes, built in-place in ar by tensor doubling.
  // loc bit k = data bit k = wire 7-k. quad bit0 = wire1, bit1 = wire0.
  float ar[64], ai[64];
  ar[0] = ((qq & 1) ? sw[1] : cw[1]) * ((qq & 2) ? sw[0] : cw[0]);
#pragma unroll
  for (int k = 0; k < 6; ++k) {
    const float cc = cw[7 - k], ss = sw[7 - k];
#pragma unroll
    for (int t = (1 << k) - 1; t >= 0; --t) {
      ar[t + (1 << k)] = ar[t] * ss;
      ar[t] = ar[t] * cc;
    }
  }
  // Phase (-i)^popcount(d): local part compile-time, quad part lane-uniform.
  {
    const int pq = __builtin_popcount(qq);
#pragma unroll
    for (int l = 63; l >= 0; --l) {
      const int pl = __builtin_popcount(l) & 3;
      const float mm = ar[l];
      if (pl == 0) { ar[l] = mm;   ai[l] = 0.0f; }
      else if (pl == 1) { ar[l] = 0.0f; ai[l] = -mm; }
      else if (pl == 2) { ar[l] = -mm;  ai[l] = 0.0f; }
      else { ar[l] = 0.0f; ai[l] = mm; }
    }
    // lane-uniform rotation by (-i)^pq: pq=1: (r,i)->(i,-r); pq=2: negate.
    if (pq == 1) {
#pragma unroll
      for (int l = 0; l < 64; ++l) {
        const float t = ar[l];
        ar[l] = ai[l];
        ai[l] = -t;
      }
    } else if (pq == 2) {
#pragma unroll
      for (int l = 0; l < 64; ++l) {
        ar[l] = -ar[l];
        ai[l] = -ai[l];
      }
    }
  }

  // Layer 1 RX (weight idx 0..7 = wires 0..7), masks e_{7-w}.
  gate_q<QX2, 0>(wc[0], wsn[0], ar, ai);      // 0x80
  gate_q<QX1, 0>(wc[1], wsn[1], ar, ai);      // 0x40
  gate_l<0x20>(wc[2], wsn[2], ar, ai);
  gate_l<0x10>(wc[3], wsn[3], ar, ai);
  gate_l<0x08>(wc[4], wsn[4], ar, ai);
  gate_l<0x04>(wc[5], wsn[5], ar, ai);
  gate_l<0x02>(wc[6], wsn[6], ar, ai);
  gate_l<0x01>(wc[7], wsn[7], ar, ai);
  // Layer 2 RX (idx 8..15), masks B1*e_w (verified round 1).
  gate_q<QX3, 0>(wc[8], wsn[8], ar, ai);      // 0xC0
  gate_q<QX1, 0x20>(wc[9], wsn[9], ar, ai);   // 0x60
  gate_l<0x30>(wc[10], wsn[10], ar, ai);
  gate_l<0x18>(wc[11], wsn[11], ar, ai);
  gate_l<0x0C>(wc[12], wsn[12], ar, ai);
  gate_l<0x06>(wc[13], wsn[13], ar, ai);
  gate_l<0x03>(wc[14], wsn[14], ar, ai);
  gate_q<QX3, 0x01>(wc[15], wsn[15], ar, ai); // 0xC1

  // Probabilities + full 6-stage local WHT: p[u] = sum_l (-1)^<u,l> |amp_l|^2.
  float p[64];
#pragma unroll
  for (int l = 0; l < 64; ++l) p[l] = ar[l] * ar[l] + ai[l] * ai[l];
#pragma unroll
  for (int k = 0; k < 6; ++k) {
#pragma unroll
    for (int l = 0; l < 64; ++l) {
      if (!(l & (1 << k))) {
        const int q2 = l | (1 << k);
        const float a = p[l], b = p[q2];
        p[l] = a + b;
        p[q2] = a - b;
      }
    }
  }
  // Readout masks r_i -> (quad part rq = r>>6, local part rl = r&0x3F):
  // i: 0:(3,0x15) 1:(2,0x3F) 2:(1,0x1F) 3:(2,0x2F) 4:(1,0x17) 5:(2,0x2B)
  //    6:(1,0x15) 7:(2,0x2A)
  const float o15 = quad_wht(p[0x15], qq);  // serves i0 (qq=3) and i6 (qq=1)
  const float o3F = quad_wht(p[0x3F], qq);
  const float o1F = quad_wht(p[0x1F], qq);
  const float o2F = quad_wht(p[0x2F], qq);
  const float o17 = quad_wht(p[0x17], qq);
  const float o2B = quad_wht(p[0x2B], qq);
  const float o2A = quad_wht(p[0x2A], qq);

  float* orow = outp + (size_t)samp * 8;
  if (qq == 3) orow[0] = o15;
  if (qq == 2) {
    orow[1] = o3F;
    orow[3] = o2F;
    orow[5] = o2B;
    orow[7] = o2A;
  }
  if (qq == 1) {
    orow[2] = o1F;
    orow[4] = o17;
    orow[6] = o15;
  }
}

// Per-block weight trig into LDS (threads 0..31), then qsim per wave.
__device__ __forceinline__ void weight_trig(const float* __restrict__ w,
                                            float* __restrict__ tc,
                                            float* __restrict__ tsn) {
  if (threadIdx.x < 32) {
    const int a = threadIdx.x & 15;
    const float half = 0.5f * w[a];
    if (threadIdx.x < 16)
      tc[a] = cosf(half);
    else
      tsn[a] = sinf(half);
  }
  __syncthreads();
}

__global__ __launch_bounds__(256, 2) void mhaq_qproj3_kernel(
    const float* __restrict__ q, const float* __restrict__ k,
    const float* __restrict__ v, const float* __restrict__ wq,
    const float* __restrict__ wk, const float* __restrict__ wv,
    float* __restrict__ qp, float* __restrict__ kp, float* __restrict__ vp) {
  __shared__ float tc[16], tsn[16];
  const int wg = blockIdx.x * 4 + (threadIdx.x >> 6);  // 0..6143
  const int proj = wg >> 11;  // 2048 waves per projection; block-uniform
  const float* wsel = proj == 0 ? wq : proj == 1 ? wk : wv;
  weight_trig(wsel, tc, tsn);
  const float* in = proj == 0 ? q : proj == 1 ? k : v;
  float* op = proj == 0 ? qp : proj == 1 ? kp : vp;
  qsim_wave(in, op, (wg & 2047) * 16, tc, tsn);
}

__global__ __launch_bounds__(256, 2) void mhaq_qproj1_kernel(
    const float* __restrict__ ctx, const float* __restrict__ wd,
    float* __restrict__ outp) {
  __shared__ float tc[16], tsn[16];
  weight_trig(wd, tc, tsn);
  const int wg = blockIdx.x * 4 + (threadIdx.x >> 6);  // 0..2047
  qsim_wave(ctx, outp, wg * 16, tc, tsn);
}

// Full-wave reductions: quad DPP + row mirrors + 2 shfl stages (only DS use).
__device__ __forceinline__ float wred_sum(float v) {
  v += dppf<QX1>(v);
  v += dppf<QX2>(v);
  v += dppf<ROW_HALF_MIRROR>(v);  // xor7 == xor4 after quad-uniform
  v += dppf<ROW_MIRROR>(v);       // xor15 == xor8 after 8-uniform
  v += __shfl_xor(v, 16, 64);
  v += __shfl_xor(v, 32, 64);
  return v;
}
__device__ __forceinline__ float wred_max(float v) {
  v = fmaxf(v, dppf<QX1>(v));
  v = fmaxf(v, dppf<QX2>(v));
  v = fmaxf(v, dppf<ROW_HALF_MIRROR>(v));
  v = fmaxf(v, dppf<ROW_MIRROR>(v));
  v = fmaxf(v, __shfl_xor(v, 16, 64));
  v = fmaxf(v, __shfl_xor(v, 32, 64));
  return v;
}

// Attention: one wave per (b,h, 8-row chunk); K/V head slice in VGPRs.
// Lane owns j = t*256 + lane*4 + c (t,c in 0..3) so the attn-row store for
// each t is one dense, aligned 1 KB block per wave instruction (full-line
// HBM writes). Reductions/PV are ownership-agnostic.
__global__ __launch_bounds__(256, 2) void mhaq_attn_kernel(
    const float* __restrict__ qp, const float* __restrict__ kp,
    const float* __restrict__ vp, float* __restrict__ ctx,
    float* __restrict__ attn) {
  const int wg = blockIdx.x * 4 + (threadIdx.x >> 6);  // 0..8191
  const int bh = wg >> 7;      // 64 (b,h) pairs, 128 chunks each
  const int chunk = wg & 127;  // 8 rows per chunk
  const int b = bh >> 1, h = bh & 1;
  const int lane = threadIdx.x & 63;

  float4 kreg[16], vreg[16];
  const float* kbase = kp + (size_t)b * 1024 * 8 + h * 4;
  const float* vbase = vp + (size_t)b * 1024 * 8 + h * 4;
#pragma unroll
  for (int t = 0; t < 4; ++t) {
#pragma unroll
    for (int c = 0; c < 4; ++c) {
      const size_t j = (size_t)t * 256 + lane * 4 + c;
      kreg[t * 4 + c] = *(const float4*)(kbase + j * 8);
      vreg[t * 4 + c] = *(const float4*)(vbase + j * 8);
    }
  }

  for (int r = 0; r < 8; ++r) {
    const int i = chunk * 8 + r;
    const float4 qv = *(const float4*)(qp + ((size_t)b * 1024 + i) * 8 + h * 4);
    float e[16];
    float mx = -1e30f;
#pragma unroll
    for (int t = 0; t < 16; ++t) {
      float s = qv.x * kreg[t].x + qv.y * kreg[t].y + qv.z * kreg[t].z +
                qv.w * kreg[t].w;
      s *= 0.5f;  // 1/sqrt(D), D=4
      e[t] = s;
      mx = fmaxf(mx, s);
    }
    mx = wred_max(mx);
    float sum = 0.0f;
#pragma unroll
    for (int t = 0; t < 16; ++t) {
      e[t] = __expf(e[t] - mx);
      sum += e[t];
    }
    sum = wred_sum(sum);
    const float rinv = 1.0f / sum;

    float a0 = 0.f, a1 = 0.f, a2 = 0.f, a3 = 0.f;
    float* arow = attn + ((size_t)(bh * 1024 + i)) * 1024;
#pragma unroll
    for (int t = 0; t < 4; ++t) {
      float p0 = e[4 * t] * rinv, p1 = e[4 * t + 1] * rinv,
            p2 = e[4 * t + 2] * rinv, p3 = e[4 * t + 3] * rinv;
      // Dense store: 64 lanes x float4 = contiguous 1 KB at arow + t*1024B.
      *(float4*)(arow + t * 256 + lane * 4) = make_float4(p0, p1, p2, p3);
      a0 = fmaf(p0, vreg[4 * t].x, a0);
      a1 = fmaf(p0, vreg[4 * t].y, a1);
      a2 = fmaf(p0, vreg[4 * t].z, a2);
      a3 = fmaf(p0, vreg[4 * t].w, a3);
      a0 = fmaf(p1, vreg[4 * t + 1].x, a0);
      a1 = fmaf(p1, vreg[4 * t + 1].y, a1);
      a2 = fmaf(p1, vreg[4 * t + 1].z, a2);
      a3 = fmaf(p1, vreg[4 * t + 1].w, a3);
      a0 = fmaf(p2, vreg[4 * t + 2].x, a0);
      a1 = fmaf(p2, vreg[4 * t + 2].y, a1);
      a2 = fmaf(p2, vreg[4 * t + 2].z, a2);
      a3 = fmaf(p2, vreg[4 * t + 2].w, a3);
      a0 = fmaf(p3, vreg[4 * t + 3].x, a0);
      a1 = fmaf(p3, vreg[4 * t + 3].y, a1);
      a2 = fmaf(p3, vreg[4 * t + 3].z, a2);
      a3 = fmaf(p3, vreg[4 * t + 3].w, a3);
    }
    a0 = wred_sum(a0);
    a1 = wred_sum(a1);
    a2 = wred_sum(a2);
    a3 = wred_sum(a3);
    if (lane == 0)
      *(float4*)(ctx + ((size_t)b * 1024 + i) * 8 + h * 4) =
          make_float4(a0, a1, a2, a3);
  }
}

extern "C" void kernel_launch(void* const* d_in, const int* in_sizes, int n_in,
                              void* d_out, int out_size, void* d_ws,
                              size_t ws_size, hipStream_t stream) {
  (void)in_sizes; (void)n_in; (void)out_size; (void)ws_size;
  const float* q = (const float*)d_in[0];
  const float* k = (const float*)d_in[1];
  const float* v = (const float*)d_in[2];
  const float* wq = (const float*)d_in[3];
  const float* wk = (const float*)d_in[4];
  const float* wv = (const float*)d_in[5];
  const float* wd = (const float*)d_in[6];
  float* outp = (float*)d_out;  // [0, 262144): out; then attn (B,H,S,S)
  float* attn = outp + 262144;

  float* wsf = (float*)d_ws;
  float* qp = wsf;
  float* kp = qp + (size_t)NSAMP * 8;
  float* vp = kp + (size_t)NSAMP * 8;
  float* ctx = vp + (size_t)NSAMP * 8;  // concat layout [b,s,h*4+d]

  hipLaunchKernelGGL(mhaq_qproj3_kernel, dim3(1536), dim3(256), 0, stream, q,
                     k, v, wq, wk, wv, qp, kp, vp);
  hipLaunchKernelGGL(mhaq_attn_kernel, dim3(2048), dim3(256), 0, stream, qp,
                     kp, vp, ctx, attn);
  hipLaunchKernelGGL(mhaq_qproj1_kernel, dim3(512), dim3(256), 0, stream, ctx,
                     wd, outp);
}